// Round 7
// baseline (1757.690 us; speedup 1.0000x reference)
//
#include <hip/hip_runtime.h>
#include <hip/hip_bf16.h>
#include <cstdint>

// Problem constants
#define B_   1024
#define V_   16
#define NH_  32
#define SH_  8
#define D_   128
#define KV_  1024
#define H_   4096

typedef __bf16 bf16;
typedef bf16  bf16x8 __attribute__((ext_vector_type(8)));
typedef float f32x2  __attribute__((ext_vector_type(2)));
typedef float f32x4  __attribute__((ext_vector_type(4)));

#define VMCNT(n) asm volatile("s_waitcnt vmcnt(" #n ")" ::: "memory")
#define LGKM0()  asm volatile("s_waitcnt lgkmcnt(0)" ::: "memory")

// async global->LDS, 16B per lane. LDS dest is wave-uniform base + lane*16.
__device__ __forceinline__ void gl2lds16(const void* g, void* l) {
    __builtin_amdgcn_global_load_lds((const __attribute__((address_space(1))) void*)g,
                                     (__attribute__((address_space(3))) void*)l,
                                     16, 0, 0);
}

// ---------------------------------------------------------------------------
// K1: h1[v][b][k] = tanh(prefix[b][v] * W1[v][k] + b1[v][k])  (bf16 out)
// ---------------------------------------------------------------------------
__global__ __launch_bounds__(256)
void h1_kernel(const float* __restrict__ prefix, const float* __restrict__ W1,
               const float* __restrict__ b1, bf16* __restrict__ h1)
{
    int gid = blockIdx.x * 256 + threadIdx.x;   // V_*B_*KV_/8 = 2M threads
    int k8  = gid & 127;                        // KV_/8 = 128
    int b   = (gid >> 7) & 1023;
    int v   = gid >> 17;
    float x = prefix[b * V_ + v];
    const float* wp = W1 + (size_t)v * KV_ + k8 * 8;
    const float* bp = b1 + (size_t)v * KV_ + k8 * 8;
    f32x4 w0 = *(const f32x4*)wp,       w1 = *(const f32x4*)(wp + 4);
    f32x4 q0 = *(const f32x4*)bp,       q1 = *(const f32x4*)(bp + 4);
    bf16x8 o;
#pragma unroll
    for (int j = 0; j < 4; ++j) o[j]     = (bf16)tanhf(fmaf(x, w0[j], q0[j]));
#pragma unroll
    for (int j = 0; j < 4; ++j) o[4 + j] = (bf16)tanhf(fmaf(x, w1[j], q1[j]));
    *(bf16x8*)(h1 + (size_t)gid * 8) = o;
}

// ---------------------------------------------------------------------------
// K2: pipelined GEMM, fused B-transpose+fp32->bf16, counted-vmcnt schedule.
//   C[v] = A[v] (M=1024 x KDIM, bf16 row-major) * Bf[v] ([KDIM][NDIM] fp32)
// MODE 0: out = tanh(C + bias) -> bf16 [V][M][NDIM]   (h2)
// MODE 1: out = C + bias -> fp32 scattered to [B,NH,V,D], 4-way head rep,
//         via per-wave LDS transpose so every store is 128B contiguous.
//
// 128x128 tile, BK=64, 4 waves (2x2), 4x4 16x16x32 MFMA frags per wave.
// 48KB LDS (A dbuf 2x16K, B single 16K) -> 3 blocks/CU (12 waves/CU) --
// occupancy is the latency-hiding lever round 5/6 lacked. Per step:
//   stageA(kt+1) | issue br(kt+2) | setprio1 MFMA(kt) setprio0
//   | s_barrier (#1: all waves done reading bL)
//   | VMCNT(20) retire br(kt+1) | writeB(kt+1)->bL | VMCNT(16) retire A(kt+1)
//   | LGKM0 | s_barrier (#2: publish).
// No vmcnt(0) in steady state; br gets ~1.5 steps in flight, A ~1 step.
// ---------------------------------------------------------------------------
template<int MODE, int KDIM, int NDIM>
__global__ __launch_bounds__(256)
void gemm_p3(const bf16* __restrict__ A, const float* __restrict__ Bf,
             const float* __restrict__ bias,
             bf16* __restrict__ outB, float* __restrict__ outF)
{
    // aBuf: 2 x 16KB at [0, 32768); bBuf: 1 x 16KB at [32768, 49152)
    __shared__ __align__(16) char smem[49152];

    const int v  = blockIdx.z;
    const int m0 = blockIdx.y * 128;
    const int n0 = blockIdx.x * 128;
    const int t  = threadIdx.x;
    const int l  = t & 63;
    const int w  = t >> 6;          // wave id; also the k-quarter for B staging
    const int wm = (w >> 1) * 64;
    const int wn = (w & 1) * 64;
    constexpr int NT = KDIM / 64;
    static_assert(NT >= 4 && (NT % 2) == 0, "NT must be even and >= 4");

    const bf16*  Av = A  + (size_t)v * 1024 * KDIM + (size_t)m0 * KDIM;
    const float* Bv = Bf + (size_t)v * KDIM * NDIM + n0;

    f32x4 acc[4][4];
#pragma unroll
    for (int i = 0; i < 4; ++i)
#pragma unroll
        for (int j = 0; j < 4; ++j) acc[i][j] = f32x4{0.f, 0.f, 0.f, 0.f};

    // B staging: wave w covers k-rows [w*16, w*16+16), lane l covers n=2l,2l+1
    const float* bptr = Bv + (size_t)(w * 16) * NDIM + 2 * l;
    f32x2 brA[16], brB[16];

    auto loadBR = [&](int ktile, f32x2 (&bank)[16]) {
        const float* np = bptr + (size_t)ktile * 64 * NDIM;
#pragma unroll
        for (int j = 0; j < 16; ++j) bank[j] = *(const f32x2*)(np + (size_t)j * NDIM);
    };
    auto stageA = [&](int ktile, int ab) {
#pragma unroll
        for (int i = 0; i < 4; ++i) {
            const int off = t + i * 256;
            const int row = off >> 3;
            const int gc  = (off & 7) ^ ((row >> 1) & 7);
            gl2lds16(Av + (size_t)row * KDIM + ktile * 64 + gc * 8,
                     smem + (size_t)ab * 16384 + (size_t)(w * 64 + i * 256) * 16);
        }
    };
    auto writeB = [&](f32x2 (&bank)[16]) {
        bf16* bN = (bf16*)(smem + 32768);
#pragma unroll
        for (int i = 0; i < 2; ++i)
#pragma unroll
            for (int h = 0; h < 2; ++h) {
                bf16x8 pk;
#pragma unroll
                for (int jj = 0; jj < 8; ++jj) pk[jj] = (bf16)bank[h * 8 + jj][i];
                const int n  = 2 * l + i;
                const int ch = (w * 2 + h) ^ (l & 7);
                *(bf16x8*)(bN + n * 64 + ch * 8) = pk;
            }
    };
    auto mfmaStep = [&](int kt) {
        const bf16* aC = (const bf16*)(smem + (size_t)(kt & 1) * 16384);
        const bf16* bC = (const bf16*)(smem + 32768);
        __builtin_amdgcn_s_setprio(1);
#pragma unroll
        for (int kk = 0; kk < 2; ++kk) {
            bf16x8 af[4], bfv[4];
#pragma unroll
            for (int f = 0; f < 4; ++f) {
                const int mr = wm + f * 16 + (l & 15);
                const int ca = (kk * 4 + (l >> 4)) ^ ((mr >> 1) & 7);
                af[f]  = *(const bf16x8*)(aC + mr * 64 + ca * 8);
                const int nr = wn + f * 16 + (l & 15);
                const int cb = (kk * 4 + (l >> 4)) ^ ((nr >> 1) & 7);
                bfv[f] = *(const bf16x8*)(bC + nr * 64 + cb * 8);
            }
#pragma unroll
            for (int fm = 0; fm < 4; ++fm)
#pragma unroll
                for (int fn = 0; fn < 4; ++fn)
                    acc[fm][fn] = __builtin_amdgcn_mfma_f32_16x16x32_bf16(
                        af[fm], bfv[fn], acc[fm][fn], 0, 0, 0);
        }
        __builtin_amdgcn_s_setprio(0);
    };

    // ---- prologue: invariant at entry of step kt: aL[kt&1]=A(kt), bL=B(kt),
    //      brUse regs = B(kt+1) values, br(kt+1) loads retired or in flight.
    stageA(0, 0);                 // A(0)  [4]
    loadBR(0, brA);               // br(0) [16]
    loadBR(1, brB);               // br(1) [16]   outstanding: 36
    VMCNT(16);                    // retire A(0)+br(0); br(1) keeps flying
    writeB(brA);                  // B(0) -> bL
    LGKM0();
    __builtin_amdgcn_s_barrier(); // tile 0 published; outstanding: br(1)[16]

    // ---- steady loop, unrolled by 2 for static br bank selection ----
    auto stepS = [&](int kt, f32x2 (&brIss)[16], f32x2 (&brUse)[16]) {
        stageA(kt + 1, (kt + 1) & 1);   // A(kt+1) [4]
        loadBR(kt + 2, brIss);          // br(kt+2) [16]; outstanding 36
        mfmaStep(kt);                   // loads fly under MFMA
        __builtin_amdgcn_s_barrier();   // #1: all waves done reading bL
        VMCNT(20);                      // retire br(kt+1)
        writeB(brUse);                  // B(kt+1) -> bL
        VMCNT(16);                      // retire A(kt+1); br(kt+2) stays out
        LGKM0();
        __builtin_amdgcn_s_barrier();   // #2: publish aL[nxt], bL
    };
    for (int kt = 0; kt + 3 < NT; kt += 2) {
        stepS(kt,     brA, brB);
        stepS(kt + 1, brB, brA);
    }
    {   // penultimate step kt = NT-2: entry outstanding br(NT-1) in brB
        stageA(NT - 1, (NT - 1) & 1);
        mfmaStep(NT - 2);
        __builtin_amdgcn_s_barrier();   // #1
        VMCNT(4);                       // retire br(NT-1)
        writeB(brB);
        VMCNT(0);                       // retire A(NT-1)
        LGKM0();
        __builtin_amdgcn_s_barrier();   // #2
    }
    mfmaStep(NT - 1);                   // last step: compute only

    // ---- epilogue. C/D frag: col = lane&15, row = (lane>>4)*4 + reg ----
    const int rbase = (l >> 4) * 4;
    const int cbase = l & 15;
    if (MODE == 0) {
#pragma unroll
        for (int fn = 0; fn < 4; ++fn) {
            const int nc = n0 + wn + fn * 16 + cbase;
            const float bv = bias[(size_t)v * NDIM + nc];
#pragma unroll
            for (int fm = 0; fm < 4; ++fm)
#pragma unroll
                for (int j = 0; j < 4; ++j) {
                    const int mr = m0 + wm + fm * 16 + rbase + j;
                    outB[(size_t)v * 1024 * NDIM + (size_t)mr * NDIM + nc] =
                        (bf16)tanhf(acc[fm][fn][j] + bv);
                }
        }
    } else {
        __syncthreads();   // LDS buffers may still be read by other waves
        // per-wave 64x32 f32 scratch (8KB), two 32-col passes; swizzled
        // (c ^ ((r>>2)&1)<<4) -> 2-way max on write (free), uniform on read.
        float* scr = (float*)(smem + (size_t)w * 8192);
        const int nb = n0 + wn;          // wave col base (multiple of 64)
        const int sh = nb >> 7;          // slider head
        const int db = nb & 127;         // 0 or 64
#pragma unroll
        for (int p = 0; p < 2; ++p) {
#pragma unroll
            for (int fm = 0; fm < 4; ++fm)
#pragma unroll
                for (int fq = 0; fq < 2; ++fq) {
                    const int fn = 2 * p + fq;
#pragma unroll
                    for (int j = 0; j < 4; ++j) {
                        const int r = fm * 16 + rbase + j;
                        const int c = fq * 16 + cbase;      // 0..31
                        scr[r * 32 + (c ^ (((r >> 2) & 1) << 4))] = acc[fm][fn][j];
                    }
                }
            const int c4   = (l & 7) * 4;
            const int colg = p * 32 + c4;    // col within wave's 64-col strip
            f32x4 bv4;
#pragma unroll
            for (int q = 0; q < 4; ++q)
                bv4[q] = bias[(size_t)v * NDIM + nb + colg + q];
#pragma unroll
            for (int i = 0; i < 8; ++i) {
                const int r = i * 8 + (l >> 3);
                f32x4 val = *(const f32x4*)&scr[r * 32 + (c4 ^ (((r >> 2) & 1) << 4))];
#pragma unroll
                for (int q = 0; q < 4; ++q) val[q] += bv4[q];
                const int mr = m0 + wm + r;
                float* pp = outF + (size_t)mr * (NH_ * V_ * D_)
                                 + (size_t)(sh * 4) * (V_ * D_)
                                 + (size_t)v * D_ + db + colg;
                *(f32x4*)(pp)               = val;
                *(f32x4*)(pp + V_ * D_)     = val;
                *(f32x4*)(pp + 2 * V_ * D_) = val;
                *(f32x4*)(pp + 3 * V_ * D_) = val;
            }
        }
    }
}

// ---------------------------------------------------------------------------
__global__ void tail_kernel(const float* __restrict__ af, float* __restrict__ out)
{
    out[0] = af[0];
}

// ---------------------------------------------------------------------------
extern "C" void kernel_launch(void* const* d_in, const int* in_sizes, int n_in,
                              void* d_out, int out_size, void* d_ws, size_t ws_size,
                              hipStream_t stream)
{
    const float* prefix = (const float*)d_in[0];
    const float* W1[2]  = {(const float*)d_in[1], (const float*)d_in[7]};
    const float* b1[2]  = {(const float*)d_in[2], (const float*)d_in[8]};
    const float* W2[2]  = {(const float*)d_in[3], (const float*)d_in[9]};
    const float* b2[2]  = {(const float*)d_in[4], (const float*)d_in[10]};
    const float* W3[2]  = {(const float*)d_in[5], (const float*)d_in[11]};
    const float* b3[2]  = {(const float*)d_in[6], (const float*)d_in[12]};
    const float* afac   = (const float*)d_in[13];

    // workspace: h1 = V*B*KV bf16 (32 MiB), h2 = V*B*H bf16 (128 MiB)
    bf16* h1 = (bf16*)d_ws;
    bf16* h2 = (bf16*)((char*)d_ws + (size_t)33554432);
    float* outp = (float*)d_out;

    for (int m = 0; m < 2; ++m) {
        // h1 = tanh(x*W1 + b1)
        h1_kernel<<<8192, 256, 0, stream>>>(prefix, W1[m], b1[m], h1);
        // h2 = tanh(h1 @ W2 + b2)   (B-transpose fused into staging)
        gemm_p3<0, 1024, 4096><<<dim3(32, 8, 16), 256, 0, stream>>>(
            h1, W2[m], b2[m], h2, nullptr);
        // out = h2 @ W3 + b3, scattered into keys (m=0) / values (m=1)
        gemm_p3<1, 4096, 1024><<<dim3(8, 8, 16), 256, 0, stream>>>(
            h2, W3[m], b3[m], nullptr, outp + (size_t)m * (B_ * NH_ * V_ * D_));
    }
    tail_kernel<<<1, 1, 0, stream>>>(afac, outp + (size_t)2 * B_ * NH_ * V_ * D_);
}

// Round 8
// 1045.224 us; speedup vs baseline: 1.6816x; 1.6816x over previous
//
#include <hip/hip_runtime.h>
#include <hip/hip_bf16.h>
#include <cstdint>

// Problem constants
#define B_   1024
#define V_   16
#define NH_  32
#define SH_  8
#define D_   128
#define KV_  1024
#define H_   4096

typedef __bf16 bf16;
typedef bf16  bf16x8 __attribute__((ext_vector_type(8)));
typedef float f32x2  __attribute__((ext_vector_type(2)));
typedef float f32x4  __attribute__((ext_vector_type(4)));

#define VMCNT(n) asm volatile("s_waitcnt vmcnt(" #n ")" ::: "memory")
#define LGKM0()  asm volatile("s_waitcnt lgkmcnt(0)" ::: "memory")

// async global->LDS, 16B per lane. LDS dest is wave-uniform base + lane*16.
__device__ __forceinline__ void gl2lds16(const void* g, void* l) {
    __builtin_amdgcn_global_load_lds((const __attribute__((address_space(1))) void*)g,
                                     (__attribute__((address_space(3))) void*)l,
                                     16, 0, 0);
}

// ---------------------------------------------------------------------------
// K1: h1[v][b][k] = tanh(prefix[b][v] * W1[v][k] + b1[v][k])  (bf16 out)
// ---------------------------------------------------------------------------
__global__ __launch_bounds__(256)
void h1_kernel(const float* __restrict__ prefix, const float* __restrict__ W1,
               const float* __restrict__ b1, bf16* __restrict__ h1)
{
    int gid = blockIdx.x * 256 + threadIdx.x;   // V_*B_*KV_/8 = 2M threads
    int k8  = gid & 127;                        // KV_/8 = 128
    int b   = (gid >> 7) & 1023;
    int v   = gid >> 17;
    float x = prefix[b * V_ + v];
    const float* wp = W1 + (size_t)v * KV_ + k8 * 8;
    const float* bp = b1 + (size_t)v * KV_ + k8 * 8;
    f32x4 w0 = *(const f32x4*)wp,       w1 = *(const f32x4*)(wp + 4);
    f32x4 q0 = *(const f32x4*)bp,       q1 = *(const f32x4*)(bp + 4);
    bf16x8 o;
#pragma unroll
    for (int j = 0; j < 4; ++j) o[j]     = (bf16)tanhf(fmaf(x, w0[j], q0[j]));
#pragma unroll
    for (int j = 0; j < 4; ++j) o[4 + j] = (bf16)tanhf(fmaf(x, w1[j], q1[j]));
    *(bf16x8*)(h1 + (size_t)gid * 8) = o;
}

// ---------------------------------------------------------------------------
// K2: pipelined GEMM, fused B-transpose+fp32->bf16, counted-vmcnt schedule.
//   C[v] = A[v] (M=1024 x KDIM, bf16 row-major) * Bf[v] ([KDIM][NDIM] fp32)
// MODE 0: out = tanh(C + bias) -> bf16 [V][M][NDIM]   (h2)
// MODE 1: out = C + bias -> fp32 scattered to [B,NH,V,D], 4-way head rep,
//         via per-wave LDS transpose so every store is 128B contiguous.
//
// 256x128 tile (vs 128x128 in R6): request volume -33% -- R4/R6 counters
// show ~10 TB/s aggregate request service rate (L3-bound), so fewer
// operand re-reads is the lever, not schedule. 512 threads, 8 waves (4x2),
// 64x64 out/wave, 4x4 16x16x32 MFMA frags, BK=64.
// LDS 96KB: A dbuf 2x32K, B dbuf 2x16K -> 1 block/CU, 8 waves (2/SIMD).
// Steady step kt (entry: br(kt+1)[8] in flight, tiles kt in LDS):
//   stageA(kt+1)[4 gl2lds] | loadBR(kt+2)[8] | MFMA(kt)
//   | VMCNT(12) retire br(kt+1) | writeB(kt+1) | VMCNT(8) retire A(kt+1)
//   | LGKM0 | s_barrier.  No vmcnt(0) in steady state.
// ---------------------------------------------------------------------------
template<int MODE, int KDIM, int NDIM>
__global__ __launch_bounds__(512)
void gemm_w(const bf16* __restrict__ A, const float* __restrict__ Bf,
            const float* __restrict__ bias,
            bf16* __restrict__ outB, float* __restrict__ outF)
{
    // aBuf: 2 x 32KB at [0, 65536); bBuf: 2 x 16KB at [65536, 98304)
    __shared__ __align__(16) char smem[98304];

    const int v  = blockIdx.z;
    const int m0 = blockIdx.y * 256;
    const int n0 = blockIdx.x * 128;
    const int t  = threadIdx.x;
    const int l  = t & 63;
    const int w  = t >> 6;          // wave id 0..7; also k-octave for B staging
    const int wr = w >> 1;          // wave row 0..3  (64 rows each)
    const int wc = w & 1;           // wave col 0..1  (64 cols each)
    constexpr int NT = KDIM / 64;
    static_assert(NT >= 4 && (NT % 2) == 0, "NT must be even and >= 4");

    const bf16*  Av = A  + (size_t)v * 1024 * KDIM + (size_t)m0 * KDIM;
    const float* Bv = Bf + (size_t)v * KDIM * NDIM + n0;

    f32x4 acc[4][4];
#pragma unroll
    for (int i = 0; i < 4; ++i)
#pragma unroll
        for (int j = 0; j < 4; ++j) acc[i][j] = f32x4{0.f, 0.f, 0.f, 0.f};

    // B staging: wave w covers k-rows [w*8, w*8+8), lane l covers n=2l,2l+1
    const float* bptr = Bv + (size_t)(w * 8) * NDIM + 2 * l;
    f32x2 brA[8], brB[8];

    auto loadBR = [&](int ktile, f32x2 (&bank)[8]) {
        const float* np = bptr + (size_t)ktile * 64 * NDIM;
#pragma unroll
        for (int j = 0; j < 8; ++j) bank[j] = *(const f32x2*)(np + (size_t)j * NDIM);
    };
    auto stageA = [&](int ktile, int ab) {
#pragma unroll
        for (int i = 0; i < 4; ++i) {
            const int off = t + i * 512;            // 0..2047 (16B chunks)
            const int row = off >> 3;               // 0..255
            const int gc  = (off & 7) ^ ((row >> 1) & 7);
            gl2lds16(Av + (size_t)row * KDIM + ktile * 64 + gc * 8,
                     smem + (size_t)ab * 32768 + (size_t)off * 16);
        }
    };
    auto writeB = [&](f32x2 (&bank)[8], int bb) {
        bf16* bN = (bf16*)(smem + 65536 + (size_t)bb * 16384);
#pragma unroll
        for (int i = 0; i < 2; ++i) {
            bf16x8 pk;
#pragma unroll
            for (int jj = 0; jj < 8; ++jj) pk[jj] = (bf16)bank[jj][i];
            const int n  = 2 * l + i;               // 0..127
            const int ch = w ^ (l & 7);             // data chunk w, slot swz
            *(bf16x8*)(bN + n * 64 + ch * 8) = pk;
        }
    };
    auto mfmaStep = [&](int kt) {
        const bf16* aC = (const bf16*)(smem + (size_t)(kt & 1) * 32768);
        const bf16* bC = (const bf16*)(smem + 65536 + (size_t)(kt & 1) * 16384);
#pragma unroll
        for (int kk = 0; kk < 2; ++kk) {
            bf16x8 af[4], bfv[4];
#pragma unroll
            for (int f = 0; f < 4; ++f) {
                const int mr = wr * 64 + f * 16 + (l & 15);
                const int ca = (kk * 4 + (l >> 4)) ^ ((mr >> 1) & 7);
                af[f]  = *(const bf16x8*)(aC + mr * 64 + ca * 8);
                const int nr = wc * 64 + f * 16 + (l & 15);
                const int cb = (kk * 4 + (l >> 4)) ^ ((nr >> 1) & 7);
                bfv[f] = *(const bf16x8*)(bC + nr * 64 + cb * 8);
            }
#pragma unroll
            for (int fm = 0; fm < 4; ++fm)
#pragma unroll
                for (int fn = 0; fn < 4; ++fn)
                    acc[fm][fn] = __builtin_amdgcn_mfma_f32_16x16x32_bf16(
                        af[fm], bfv[fn], acc[fm][fn], 0, 0, 0);
        }
    };

    // ---- prologue: invariant at entry of step kt: aBuf[kt&1]=A(kt),
    //      bBuf[kt&1]=B(kt), brUse = B(kt+1) values, br(kt+1) in flight.
    stageA(0, 0);                 // A(0)  [4]
    loadBR(0, brA);               // br(0) [8]
    loadBR(1, brB);               // br(1) [8]    outstanding: 20
    VMCNT(8);                     // retire A(0)+br(0); br(1) keeps flying
    writeB(brA, 0);               // B(0) -> bBuf0
    LGKM0();
    __builtin_amdgcn_s_barrier(); // tile 0 published; outstanding: br(1)[8]

    // ---- steady loop, unrolled by 2 for static br bank selection ----
    auto stepS = [&](int kt, f32x2 (&brIss)[8], f32x2 (&brUse)[8]) {
        stageA(kt + 1, (kt + 1) & 1);   // A(kt+1) [4]
        loadBR(kt + 2, brIss);          // br(kt+2) [8]; outstanding 20
        mfmaStep(kt);                   // loads fly under MFMA
        VMCNT(12);                      // retire br(kt+1)
        writeB(brUse, (kt + 1) & 1);    // B(kt+1) -> bBuf[nxt]
        VMCNT(8);                       // retire A(kt+1); br(kt+2) stays out
        LGKM0();
        __builtin_amdgcn_s_barrier();   // publish tiles kt+1
    };
    for (int kt = 0; kt + 3 < NT; kt += 2) {
        stepS(kt,     brA, brB);
        stepS(kt + 1, brB, brA);
    }
    {   // penultimate step kt = NT-2: entry outstanding br(NT-1)[8] in brB
        stageA(NT - 1, (NT - 1) & 1);   // outstanding 12
        mfmaStep(NT - 2);
        VMCNT(4);                       // retire br(NT-1), keep A(NT-1)
        writeB(brB, (NT - 1) & 1);
        VMCNT(0);                       // retire A(NT-1)
        LGKM0();
        __builtin_amdgcn_s_barrier();
    }
    mfmaStep(NT - 1);                   // last step: compute only

    // ---- epilogue. C/D frag: col = lane&15, row = (lane>>4)*4 + reg ----
    const int rbase = (l >> 4) * 4;
    const int cbase = l & 15;
    if (MODE == 0) {
#pragma unroll
        for (int fn = 0; fn < 4; ++fn) {
            const int nc = n0 + wc * 64 + fn * 16 + cbase;
            const float bv = bias[(size_t)v * NDIM + nc];
#pragma unroll
            for (int fm = 0; fm < 4; ++fm)
#pragma unroll
                for (int j = 0; j < 4; ++j) {
                    const int mr = m0 + wr * 64 + fm * 16 + rbase + j;
                    outB[(size_t)v * 1024 * NDIM + (size_t)mr * NDIM + nc] =
                        (bf16)tanhf(acc[fm][fn][j] + bv);
                }
        }
    } else {
        __syncthreads();   // main-loop LDS reads done before scratch reuse
        // per-wave 64x32 f32 scratch (8KB x 8 waves = 64KB), two 32-col
        // passes; swizzle (c ^ ((r>>2)&1)<<4): write 2-way (free), read ok.
        float* scr = (float*)(smem + (size_t)w * 8192);
        const int nb = n0 + wc * 64;     // wave col base (multiple of 64)
        const int sh = nb >> 7;          // slider head
        const int db = nb & 127;         // 0 or 64
#pragma unroll
        for (int p = 0; p < 2; ++p) {
#pragma unroll
            for (int fm = 0; fm < 4; ++fm)
#pragma unroll
                for (int fq = 0; fq < 2; ++fq) {
                    const int fn = 2 * p + fq;
#pragma unroll
                    for (int j = 0; j < 4; ++j) {
                        const int r = fm * 16 + rbase + j;
                        const int c = fq * 16 + cbase;      // 0..31
                        scr[r * 32 + (c ^ (((r >> 2) & 1) << 4))] = acc[fm][fn][j];
                    }
                }
            const int c4   = (l & 7) * 4;
            const int colg = p * 32 + c4;    // col within wave's 64-col strip
            f32x4 bv4;
#pragma unroll
            for (int q = 0; q < 4; ++q)
                bv4[q] = bias[(size_t)v * NDIM + nb + colg + q];
#pragma unroll
            for (int i = 0; i < 8; ++i) {
                const int r = i * 8 + (l >> 3);
                f32x4 val = *(const f32x4*)&scr[r * 32 + (c4 ^ (((r >> 2) & 1) << 4))];
#pragma unroll
                for (int q = 0; q < 4; ++q) val[q] += bv4[q];
                const int mr = m0 + wr * 64 + r;
                float* pp = outF + (size_t)mr * (NH_ * V_ * D_)
                                 + (size_t)(sh * 4) * (V_ * D_)
                                 + (size_t)v * D_ + db + colg;
                *(f32x4*)(pp)               = val;
                *(f32x4*)(pp + V_ * D_)     = val;
                *(f32x4*)(pp + 2 * V_ * D_) = val;
                *(f32x4*)(pp + 3 * V_ * D_) = val;
            }
        }
    }
}

// ---------------------------------------------------------------------------
__global__ void tail_kernel(const float* __restrict__ af, float* __restrict__ out)
{
    out[0] = af[0];
}

// ---------------------------------------------------------------------------
extern "C" void kernel_launch(void* const* d_in, const int* in_sizes, int n_in,
                              void* d_out, int out_size, void* d_ws, size_t ws_size,
                              hipStream_t stream)
{
    const float* prefix = (const float*)d_in[0];
    const float* W1[2]  = {(const float*)d_in[1], (const float*)d_in[7]};
    const float* b1[2]  = {(const float*)d_in[2], (const float*)d_in[8]};
    const float* W2[2]  = {(const float*)d_in[3], (const float*)d_in[9]};
    const float* b2[2]  = {(const float*)d_in[4], (const float*)d_in[10]};
    const float* W3[2]  = {(const float*)d_in[5], (const float*)d_in[11]};
    const float* b3[2]  = {(const float*)d_in[6], (const float*)d_in[12]};
    const float* afac   = (const float*)d_in[13];

    // workspace: h1 = V*B*KV bf16 (32 MiB), h2 = V*B*H bf16 (128 MiB)
    bf16* h1 = (bf16*)d_ws;
    bf16* h2 = (bf16*)((char*)d_ws + (size_t)33554432);
    float* outp = (float*)d_out;

    for (int m = 0; m < 2; ++m) {
        // h1 = tanh(x*W1 + b1)
        h1_kernel<<<8192, 256, 0, stream>>>(prefix, W1[m], b1[m], h1);
        // h2 = tanh(h1 @ W2 + b2)   (B-transpose fused into staging)
        gemm_w<0, 1024, 4096><<<dim3(32, 4, 16), 512, 0, stream>>>(
            h1, W2[m], b2[m], h2, nullptr);
        // out = h2 @ W3 + b3, scattered into keys (m=0) / values (m=1)
        gemm_w<1, 4096, 1024><<<dim3(8, 4, 16), 512, 0, stream>>>(
            h2, W3[m], b3[m], nullptr, outp + (size_t)m * (B_ * NH_ * V_ * D_));
    }
    tail_kernel<<<1, 1, 0, stream>>>(afac, outp + (size_t)2 * B_ * NH_ * V_ * D_);
}

// Round 9
// 913.420 us; speedup vs baseline: 1.9243x; 1.1443x over previous
//
#include <hip/hip_runtime.h>
#include <hip/hip_bf16.h>
#include <cstdint>

// Problem constants
#define B_   1024
#define V_   16
#define NH_  32
#define SH_  8
#define D_   128
#define KV_  1024
#define H_   4096

typedef __bf16 bf16;
typedef bf16  bf16x8 __attribute__((ext_vector_type(8)));
typedef float f32x2  __attribute__((ext_vector_type(2)));
typedef float f32x4  __attribute__((ext_vector_type(4)));

#define VMCNT(n) asm volatile("s_waitcnt vmcnt(" #n ")" ::: "memory")
#define LGKM0()  asm volatile("s_waitcnt lgkmcnt(0)" ::: "memory")

// async global->LDS, 16B per lane. LDS dest is wave-uniform base + lane*16.
__device__ __forceinline__ void gl2lds16(const void* g, void* l) {
    __builtin_amdgcn_global_load_lds((const __attribute__((address_space(1))) void*)g,
                                     (__attribute__((address_space(3))) void*)l,
                                     16, 0, 0);
}

// ---------------------------------------------------------------------------
// K1: h1[v][b][k] = tanh(prefix[b][v] * W1[v][k] + b1[v][k])  (bf16 out)
// ---------------------------------------------------------------------------
__global__ __launch_bounds__(256)
void h1_kernel(const float* __restrict__ prefix, const float* __restrict__ W1,
               const float* __restrict__ b1, bf16* __restrict__ h1)
{
    int gid = blockIdx.x * 256 + threadIdx.x;   // V_*B_*KV_/8 = 2M threads
    int k8  = gid & 127;                        // KV_/8 = 128
    int b   = (gid >> 7) & 1023;
    int v   = gid >> 17;
    float x = prefix[b * V_ + v];
    const float* wp = W1 + (size_t)v * KV_ + k8 * 8;
    const float* bp = b1 + (size_t)v * KV_ + k8 * 8;
    f32x4 w0 = *(const f32x4*)wp,       w1 = *(const f32x4*)(wp + 4);
    f32x4 q0 = *(const f32x4*)bp,       q1 = *(const f32x4*)(bp + 4);
    bf16x8 o;
#pragma unroll
    for (int j = 0; j < 4; ++j) o[j]     = (bf16)tanhf(fmaf(x, w0[j], q0[j]));
#pragma unroll
    for (int j = 0; j < 4; ++j) o[4 + j] = (bf16)tanhf(fmaf(x, w1[j], q1[j]));
    *(bf16x8*)(h1 + (size_t)gid * 8) = o;
}

// ---------------------------------------------------------------------------
// K2: pipelined GEMM, fused B-transpose+fp32->bf16.
//   C[v] = A[v] (M=1024 x KDIM, bf16 row-major) * Bf[v] ([KDIM][NDIM] fp32)
// MODE 0: out = tanh(C + bias) -> bf16 [V][M][NDIM]   (h2)
// MODE 1: out = C + bias -> fp32 scattered to [B,NH,V,D], 4-way head rep,
//         via per-wave LDS transpose so every store is 128B contiguous.
//
// 256x256 tile (R8 was 256x128): operand re-read request volume -25% --
// R4/R6/R8 counters show the GEMMs pinned at ~10 TB/s aggregate L2/L3
// request service rate, so request volume is the lever.
// 512 threads, 8 waves (2m x 4n), 128x64 out/wave, acc[8][4], BK=64.
// LDS 128KB: A dbuf 2x32K, B dbuf 2x32K -> 1 block/CU, 8 waves (2/SIMD).
// XCD-chunked swizzle (T1): each XCD gets 2 whole v-slices -> A panel
// (2MB/v) L2-resident, co-resident m-blocks share B slabs via L2.
// Steady step kt (entry: tiles kt ready in LDS, nothing in flight):
//   loadBR(kt+1)[16] | stageA(kt+1)[4 gl2lds] | MFMA(kt) (64 MFMAs, loads fly)
//   | VMCNT(4) retire br | writeB(kt+1) | VMCNT(0) (A long since issued)
//   | LGKM0 | s_barrier.
// ---------------------------------------------------------------------------
template<int MODE, int KDIM, int NDIM>
__global__ __launch_bounds__(512)
void gemm_t2(const bf16* __restrict__ A, const float* __restrict__ Bf,
             const float* __restrict__ bias,
             bf16* __restrict__ outB, float* __restrict__ outF)
{
    // aBuf: 2 x 32KB at [0, 65536); bBuf: 2 x 32KB at [65536, 131072)
    __shared__ __align__(16) char smem[131072];

    constexpr int NX  = NDIM / 256;     // n-blocks
    constexpr int NXY = NX * 4;         // blocks per v (4 m-blocks)
    const int lin = blockIdx.x + NX * blockIdx.y + NXY * blockIdx.z;
    constexpr int NWG = NXY * 16;
    constexpr int CHK = NWG / 8;        // NWG % 8 == 0 (bijective swizzle)
    const int swz = (lin & 7) * CHK + (lin >> 3);
    const int v   = swz / NXY;
    const int rem = swz - v * NXY;
    const int m0  = (rem / NX) * 256;
    const int n0  = (rem - (rem / NX) * NX) * 256;

    const int t  = threadIdx.x;
    const int l  = t & 63;
    const int w  = t >> 6;          // wave id 0..7
    const int wr = w >> 2;          // wave row 0..1 (128 rows each)
    const int wc = w & 3;           // wave col 0..3 (64 cols each)
    constexpr int NT = KDIM / 64;
    static_assert(NT >= 4, "NT >= 4");

    const bf16*  Av = A  + (size_t)v * 1024 * KDIM + (size_t)m0 * KDIM;
    const float* Bv = Bf + (size_t)v * KDIM * NDIM + n0;

    f32x4 acc[8][4];
#pragma unroll
    for (int i = 0; i < 8; ++i)
#pragma unroll
        for (int j = 0; j < 4; ++j) acc[i][j] = f32x4{0.f, 0.f, 0.f, 0.f};

    // B staging: thread t covers n = 2*(t&127)+{0,1}, k-rows (t>>7)*16..+15
    const float* bptr = Bv + (size_t)((t >> 7) * 16) * NDIM + 2 * (t & 127);
    f32x2 br[16];

    auto loadBR = [&](int ktile) {
        const float* np = bptr + (size_t)ktile * 64 * NDIM;
#pragma unroll
        for (int j = 0; j < 16; ++j) br[j] = *(const f32x2*)(np + (size_t)j * NDIM);
    };
    auto stageA = [&](int ktile, int ab) {
#pragma unroll
        for (int i = 0; i < 4; ++i) {
            const int off = t + i * 512;            // 0..2047 (16B chunks)
            const int row = off >> 3;               // 0..255
            const int gc  = (off & 7) ^ ((row >> 1) & 7);
            gl2lds16(Av + (size_t)row * KDIM + ktile * 64 + gc * 8,
                     smem + (size_t)ab * 32768 + (size_t)off * 16);
        }
    };
    auto writeB = [&](int bb) {
        bf16* bN = (bf16*)(smem + 65536 + (size_t)bb * 32768);
#pragma unroll
        for (int i = 0; i < 2; ++i)
#pragma unroll
            for (int h = 0; h < 2; ++h) {
                bf16x8 pk;
#pragma unroll
                for (int jj = 0; jj < 8; ++jj) pk[jj] = (bf16)br[h * 8 + jj][i];
                const int n  = 2 * (t & 127) + i;               // 0..255
                const int ch = ((t >> 7) * 2 + h) ^ (t & 7);    // swizzled slot
                *(bf16x8*)(bN + (size_t)n * 64 + ch * 8) = pk;
            }
    };
    auto mfmaStep = [&](int kt) {
        const bf16* aC = (const bf16*)(smem + (size_t)(kt & 1) * 32768);
        const bf16* bC = (const bf16*)(smem + 65536 + (size_t)(kt & 1) * 32768);
#pragma unroll
        for (int kk = 0; kk < 2; ++kk) {
            bf16x8 af[8], bfv[4];
#pragma unroll
            for (int f = 0; f < 8; ++f) {
                const int mr = wr * 128 + f * 16 + (l & 15);
                const int ca = (kk * 4 + (l >> 4)) ^ ((mr >> 1) & 7);
                af[f] = *(const bf16x8*)(aC + (size_t)mr * 64 + ca * 8);
            }
#pragma unroll
            for (int f = 0; f < 4; ++f) {
                const int nr = wc * 64 + f * 16 + (l & 15);
                const int cb = (kk * 4 + (l >> 4)) ^ ((nr >> 1) & 7);
                bfv[f] = *(const bf16x8*)(bC + (size_t)nr * 64 + cb * 8);
            }
#pragma unroll
            for (int fm = 0; fm < 8; ++fm)
#pragma unroll
                for (int fn = 0; fn < 4; ++fn)
                    acc[fm][fn] = __builtin_amdgcn_mfma_f32_16x16x32_bf16(
                        af[fm], bfv[fn], acc[fm][fn], 0, 0, 0);
        }
    };

    // ---- prologue: stage tile 0 ----
    loadBR(0);
    stageA(0, 0);
    VMCNT(4);                       // retire br(0); A(0) still flying
    writeB(0);
    VMCNT(0);                       // A(0) done
    LGKM0();
    __builtin_amdgcn_s_barrier();

    // ---- main loop ----
    for (int kt = 0; kt < NT - 1; ++kt) {
        loadBR(kt + 1);                 // 16 loads, fly under MFMA
        stageA(kt + 1, (kt + 1) & 1);   // 4 gl2lds, fly under MFMA
        mfmaStep(kt);                   // ~64 MFMAs
        VMCNT(4);                       // retire br(kt+1); A(kt+1) may fly
        writeB((kt + 1) & 1);
        VMCNT(0);                       // A(kt+1) done (issued a phase ago)
        LGKM0();
        __builtin_amdgcn_s_barrier();   // publish tiles kt+1
    }
    mfmaStep(NT - 1);                   // last step: compute only

    // ---- epilogue. C/D frag: col = lane&15, row = (lane>>4)*4 + reg ----
    const int rbase = (l >> 4) * 4;
    const int cbase = l & 15;
    if (MODE == 0) {
#pragma unroll
        for (int fn = 0; fn < 4; ++fn) {
            const int nc = n0 + wc * 64 + fn * 16 + cbase;
            const float bv = bias[(size_t)v * NDIM + nc];
#pragma unroll
            for (int fm = 0; fm < 8; ++fm)
#pragma unroll
                for (int j = 0; j < 4; ++j) {
                    const int mr = m0 + wr * 128 + fm * 16 + rbase + j;
                    outB[(size_t)v * 1024 * NDIM + (size_t)mr * NDIM + nc] =
                        (bf16)tanhf(acc[fm][fn][j] + bv);
                }
        }
    } else {
        __syncthreads();   // main-loop LDS reads done before scratch reuse
        // per-wave 128x32 f32 scratch (16KB x 8 waves = 128KB), two 32-col
        // passes; swizzle (c ^ ((r>>2)&1)<<4): write 2-way (free), read full.
        float* scr = (float*)(smem + (size_t)w * 16384);
        const int nb = n0 + wc * 64;     // wave col base (multiple of 64)
        const int sh = nb >> 7;          // slider head
        const int db = nb & 127;         // 0 or 64
#pragma unroll
        for (int p = 0; p < 2; ++p) {
#pragma unroll
            for (int fm = 0; fm < 8; ++fm)
#pragma unroll
                for (int fq = 0; fq < 2; ++fq) {
                    const int fn = 2 * p + fq;
#pragma unroll
                    for (int j = 0; j < 4; ++j) {
                        const int r = fm * 16 + rbase + j;      // 0..127
                        const int c = fq * 16 + cbase;          // 0..31
                        scr[r * 32 + (c ^ (((r >> 2) & 1) << 4))] = acc[fm][fn][j];
                    }
                }
            const int c4   = (l & 7) * 4;
            const int colg = p * 32 + c4;    // col within wave's 64-col strip
            f32x4 bv4;
#pragma unroll
            for (int q = 0; q < 4; ++q)
                bv4[q] = bias[(size_t)v * NDIM + nb + colg + q];
#pragma unroll
            for (int i = 0; i < 16; ++i) {
                const int r = i * 8 + (l >> 3);                 // 0..127
                f32x4 val = *(const f32x4*)&scr[r * 32 + (c4 ^ (((r >> 2) & 1) << 4))];
#pragma unroll
                for (int q = 0; q < 4; ++q) val[q] += bv4[q];
                const int mr = m0 + wr * 128 + r;
                float* pp = outF + (size_t)mr * (NH_ * V_ * D_)
                                 + (size_t)(sh * 4) * (V_ * D_)
                                 + (size_t)v * D_ + db + colg;
                *(f32x4*)(pp)               = val;
                *(f32x4*)(pp + V_ * D_)     = val;
                *(f32x4*)(pp + 2 * V_ * D_) = val;
                *(f32x4*)(pp + 3 * V_ * D_) = val;
            }
        }
    }
}

// ---------------------------------------------------------------------------
__global__ void tail_kernel(const float* __restrict__ af, float* __restrict__ out)
{
    out[0] = af[0];
}

// ---------------------------------------------------------------------------
extern "C" void kernel_launch(void* const* d_in, const int* in_sizes, int n_in,
                              void* d_out, int out_size, void* d_ws, size_t ws_size,
                              hipStream_t stream)
{
    const float* prefix = (const float*)d_in[0];
    const float* W1[2]  = {(const float*)d_in[1], (const float*)d_in[7]};
    const float* b1[2]  = {(const float*)d_in[2], (const float*)d_in[8]};
    const float* W2[2]  = {(const float*)d_in[3], (const float*)d_in[9]};
    const float* b2[2]  = {(const float*)d_in[4], (const float*)d_in[10]};
    const float* W3[2]  = {(const float*)d_in[5], (const float*)d_in[11]};
    const float* b3[2]  = {(const float*)d_in[6], (const float*)d_in[12]};
    const float* afac   = (const float*)d_in[13];

    // workspace: h1 = V*B*KV bf16 (32 MiB), h2 = V*B*H bf16 (128 MiB)
    bf16* h1 = (bf16*)d_ws;
    bf16* h2 = (bf16*)((char*)d_ws + (size_t)33554432);
    float* outp = (float*)d_out;

    for (int m = 0; m < 2; ++m) {
        // h1 = tanh(x*W1 + b1)
        h1_kernel<<<8192, 256, 0, stream>>>(prefix, W1[m], b1[m], h1);
        // h2 = tanh(h1 @ W2 + b2)   (B-transpose fused into staging)
        gemm_t2<0, 1024, 4096><<<dim3(16, 4, 16), 512, 0, stream>>>(
            h1, W2[m], b2[m], h2, nullptr);
        // out = h2 @ W3 + b3, scattered into keys (m=0) / values (m=1)
        gemm_t2<1, 4096, 1024><<<dim3(4, 4, 16), 512, 0, stream>>>(
            h2, W3[m], b3[m], nullptr, outp + (size_t)m * (B_ * NH_ * V_ * D_));
    }
    tail_kernel<<<1, 1, 0, stream>>>(afac, outp + (size_t)2 * B_ * NH_ * V_ * D_);
}